// Round 6
// baseline (669.540 us; speedup 1.0000x reference)
//
#include <hip/hip_runtime.h>
#include <hip/hip_fp16.h>

// Problem constants
#define BSZ 32
#define CS_ 640
#define CT_ 768
#define NTOK 576
#define HID 64
#define ITERS 50
#define WGB 16           // workgroups per batch
#define ROWS 36          // rows of K per workgroup (576/16)
#define NWG (BSZ*WGB)    // 512 wgs = exactly 2 per CU
#define MPITCH 640       // halves per K row (576 real + 64 pad of 0)
#define XPITCH 68        // halves per staged x row

#define MS_SCALE 14.426950408889634f      // 10*log2(e): K = exp2(M*MS_SCALE) = e^{M/reg}
#define M_FROM_MSP 0.06931471805599453f   // ln2/10:  M = log2(K)*this
#define CSCALE 8192.0f                    // uniform Sinkhorn scaling constant
// final: sum(T*M) = sum(t_hat*log2K) * M_FROM_MSP / (CSCALE*NTOK)
#define FIN_WG (M_FROM_MSP / (8192.0f * 576.0f))

// Workspace layout (bytes)
#define OFF_CNT 0              // 32 barrier counters, 64B apart (2048 B)
#define OFF_DONE 2048
#define OFF_GSUM 2056
#define OFF_DUMMY 2112         // 512 f32 keep-alive sink
#define OFF_SQS 4160           // sumsq [2][32][64] f32
#define OFF_PACC 20544         // colsum accumulators [2][32][576] f32 = 147456
#define MEMSET_BYTES 168000
#define OFF_XS 168000          // xs fp16 [32][576][64]
#define OFF_XT 2527296         // xt fp16 [32][576][64]

// k4 LDS layout (bytes); total 62,336 -> 2 wgs/CU (124,672 <= 163,840)
#define L_MS 0                 // 36*640*2 = 46080  (holds K, fp16)
#define L_U 46080              // 36*4 = 144 (alpha_hat, f32)
#define L_V 46224              // 640*4 = 2560 (beta_hat, f32)
#define L_VH 48784             // 640*2 = 1280 (beta_hat, fp16, 16B-aligned)
#define L_RED 50064            // 16*4
#define L_UNION 50128          // build: ssc(256)+stc(256)+sqs(144)+sqt(2304)+xs_l(4896)+xt_l(4352)
#define SMEM_BYTES 62336

typedef _Float16 h2_t __attribute__((ext_vector_type(2)));

#if defined(__has_builtin)
#if __has_builtin(__builtin_amdgcn_fdot2)
#define HAVE_FDOT2 1
#endif
#endif

__device__ __forceinline__ h2_t bch2(int x) { return __builtin_bit_cast(h2_t, x); }
__device__ __forceinline__ __half2 bchh(int x) { return __builtin_bit_cast(__half2, x); }

// DPP wave64 sum (VALU pipe, no LDS). ctrl/row_mask must be ICEs -> template.
template <int CTRL, int RM>
__device__ __forceinline__ float dpp_add_step(float x) {
    int y = __builtin_amdgcn_update_dpp(0, __float_as_int(x), CTRL, RM, 0xf, false);
    return x + __int_as_float(y);
}
__device__ __forceinline__ float wave_sum63(float x) {
    x = dpp_add_step<0x111, 0xf>(x);  // row_shr:1
    x = dpp_add_step<0x112, 0xf>(x);  // row_shr:2
    x = dpp_add_step<0x114, 0xf>(x);  // row_shr:4
    x = dpp_add_step<0x118, 0xf>(x);  // row_shr:8
    x = dpp_add_step<0x142, 0xa>(x);  // row_bcast:15 -> rows 1,3
    x = dpp_add_step<0x143, 0xc>(x);  // row_bcast:31 -> rows 2,3
    return x;                          // lane 63 = total
}

// ---------------------------------------------------------------------------
// K1: LDS-staged projection GEMM. Block = 256 thr (4 waves), 64-token tile.
// Each wave computes 16 h (LDS:FMA = 1:16). Register-prefetch double buffer.
// Fused: bias, fp16 write, per-(b,h) token sum-of-squares.
// ---------------------------------------------------------------------------
template <int C>
__device__ __forceinline__ void proj_body(
    const float* __restrict__ feat,   // [C][576] this batch
    const float* __restrict__ W,      // [64][C]
    const float* __restrict__ bias,
    __half* __restrict__ out,         // [576][64] this batch
    float* __restrict__ sq,           // [64]
    float (*fbuf)[64], int nblk)
{
    const int tid = threadIdx.x;
    const int lane = tid & 63;
    const int wv = __builtin_amdgcn_readfirstlane((int)(tid >> 6));
    const int h0 = wv * 16;
    const int n0 = nblk * 64;
    const int cl = tid >> 4, tq = (tid & 15) * 4;
    constexpr int NCH = C >> 6;

    float4 pf[4];
#pragma unroll
    for (int j = 0; j < 4; j++)
        pf[j] = *(const float4*)(feat + (size_t)(cl + 16 * j) * NTOK + n0 + tq);

    float acc[16];
#pragma unroll
    for (int i = 0; i < 16; i++) acc[i] = 0.f;

    for (int k = 0; k < NCH; k++) {
#pragma unroll
        for (int j = 0; j < 4; j++) *(float4*)&fbuf[cl + 16 * j][tq] = pf[j];
        __syncthreads();
        if (k + 1 < NCH) {
            const float* src = feat + (size_t)(k + 1) * 64 * NTOK;
#pragma unroll
            for (int j = 0; j < 4; j++)
                pf[j] = *(const float4*)(src + (size_t)(cl + 16 * j) * NTOK + n0 + tq);
        }
        const float* wbase = W + (size_t)h0 * C + k * 64;
#pragma unroll 2
        for (int cc8 = 0; cc8 < 64; cc8 += 8) {
            float f[8];
#pragma unroll
            for (int j = 0; j < 8; j++) f[j] = fbuf[cc8 + j][lane];
#pragma unroll
            for (int hh = 0; hh < 16; hh++) {
                const float* wr = wbase + (size_t)hh * C + cc8;
#pragma unroll
                for (int j = 0; j < 8; j++) acc[hh] = fmaf(f[j], wr[j], acc[hh]);
            }
        }
        __syncthreads();
    }
#pragma unroll
    for (int hh = 0; hh < 16; hh++) acc[hh] += bias[h0 + hh];

    __half2 hp[8];
#pragma unroll
    for (int hh = 0; hh < 16; hh += 2) hp[hh >> 1] = __floats2half2_rn(acc[hh], acc[hh + 1]);
    __half* op = out + (size_t)(n0 + lane) * HID + h0;
    *(float4*)op = ((const float4*)hp)[0];
    *(float4*)(op + 8) = ((const float4*)hp)[1];

#pragma unroll
    for (int hh = 0; hh < 16; hh++) {
        float v2 = acc[hh] * acc[hh];
#pragma unroll
        for (int off = 32; off > 0; off >>= 1) v2 += __shfl_xor(v2, off, 64);
        if (lane == 0) atomicAdd(sq + h0 + hh, v2);
    }
}

__global__ __launch_bounds__(256, 4) void k1_proj(
    const float* __restrict__ feat_s, const float* __restrict__ feat_t,
    const float* __restrict__ Ws, const float* __restrict__ bs,
    const float* __restrict__ Wt, const float* __restrict__ bt,
    __half* __restrict__ xs, __half* __restrict__ xt, float* __restrict__ sumsq)
{
    __shared__ float fbuf[64][64];
    const int nblk = blockIdx.x, b = blockIdx.y, st = blockIdx.z;
    if (st == 0) {
        proj_body<CS_>(feat_s + (size_t)b * CS_ * NTOK, Ws, bs,
                       xs + (size_t)b * NTOK * HID, sumsq + b * 64, fbuf, nblk);
    } else {
        proj_body<CT_>(feat_t + (size_t)b * CT_ * NTOK, Wt, bt,
                       xt + (size_t)b * NTOK * HID, sumsq + (BSZ + b) * 64, fbuf, nblk);
    }
}

// ---------------------------------------------------------------------------
// K4: persistent Sinkhorn in LINEAR domain. K = e^{M/reg} in LDS (fp16).
// alpha_hat = C/(K beta_hat), beta_hat = C/(K^T alpha_hat): no exp/log in the
// loop. With C uniform and beta0=1, T_hat = C*N*T exactly.
// Cross-wg: relaxed agent-scope atomics (fence-free), barrier per iteration.
// ---------------------------------------------------------------------------
__global__ __launch_bounds__(1024, 8) void k4_sinkhorn(
    const __half* __restrict__ xsh, const __half* __restrict__ xth,
    const float* __restrict__ sumsq, float* __restrict__ Pacc,
    int* __restrict__ counters, int* __restrict__ done,
    float* __restrict__ gsum, float* __restrict__ dummyout,
    float* __restrict__ out)
{
    extern __shared__ char smem[];
    __half* Ms  = (__half*)(smem + L_MS);    // holds K (fp16)
    float* u_l  = (float*)(smem + L_U);      // alpha_hat
    float* v_l  = (float*)(smem + L_V);      // beta_hat f32
    __half* v_lh = (__half*)(smem + L_VH);   // beta_hat fp16
    float* red  = (float*)(smem + L_RED);
    float* ssc  = (float*)(smem + L_UNION);
    float* stc  = (float*)(smem + L_UNION + 256);
    float* sqs  = (float*)(smem + L_UNION + 512);
    float* sqt  = (float*)(smem + L_UNION + 656);
    __half* xs_l = (__half*)(smem + L_UNION + 2960);
    __half* xt_l = (__half*)(smem + L_UNION + 7856);

    const int tid = threadIdx.x;
    const int b = blockIdx.x & 31, part = blockIdx.x >> 5;
    const int r0 = part * ROWS;
    const int lane = tid & 63, wv = tid >> 6;
    float dummy = 0.f;
    float s_kept = 0.f;

    // ---- scales; beta_hat init = 1 (cols<576), 0 (pad) ----
    if (tid < 64) {
        ssc[tid] = 1.0f / fmaxf(sqrtf(sumsq[b * 64 + tid]), 1e-12f);
    } else if (tid < 128) {
        stc[tid - 64] = 1.0f / fmaxf(sqrtf(sumsq[BSZ * 64 + b * 64 + (tid - 64)]), 1e-12f);
    }
    for (int m = tid; m < MPITCH; m += 1024) {
        float b0 = (m < NTOK) ? 1.f : 0.f;
        v_l[m] = b0;
        v_lh[m] = __float2half(b0);
    }
    __syncthreads();

    // ---- stage scaled xs slice; sqt for all 576 target tokens ----
    for (int idx = tid; idx < ROWS * 64; idx += 1024) {
        int r = idx >> 6, h = idx & 63;
        xs_l[r * XPITCH + h] =
            __float2half(__half2float(xsh[((size_t)b * NTOK + r0 + r) * 64 + h]) * ssc[h]);
    }
    if (tid < NTOK) {
        const __half* tp = xth + ((size_t)b * NTOK + tid) * 64;
        float s = 0.f;
#pragma unroll
        for (int h = 0; h < 64; h++) { float v = __half2float(tp[h]) * stc[h]; s = fmaf(v, v, s); }
        sqt[tid] = s;
    }
    __syncthreads();
    if (tid < ROWS) {
        float s = 0.f;
#pragma unroll
        for (int h = 0; h < 64; h++) { float v = __half2float(xs_l[tid * XPITCH + h]); s = fmaf(v, v, s); }
        sqs[tid] = s;
    }

    // ---- build K slice: K = exp2(clamp(M,0,..)*MS_SCALE), 18 chunks ----
    for (int c0 = 0; c0 < NTOK; c0 += 32) {
        __syncthreads();
        for (int idx = tid; idx < 32 * 64; idx += 1024) {
            int m = idx >> 6, h = idx & 63;
            xt_l[m * XPITCH + h] =
                __float2half(__half2float(xth[((size_t)b * NTOK + c0 + m) * 64 + h]) * stc[h]);
        }
        __syncthreads();
        for (int idx = tid; idx < ROWS * 32; idx += 1024) {
            int r = idx >> 5, c = idx & 31;
            const __half2* xr = (const __half2*)(xs_l + r * XPITCH);
            const __half2* tr = (const __half2*)(xt_l + c * XPITCH);
            float d = 0.f;
#pragma unroll
            for (int h2 = 0; h2 < 32; h2++) {
                float2 av = __half22float2(xr[h2]);
                float2 tv = __half22float2(tr[h2]);
                d = fmaf(av.x, tv.x, d);
                d = fmaf(av.y, tv.y, d);
            }
            float Mv = fmaxf(sqs[r] + sqt[c] - 2.f * d, 0.f);
            Ms[r * MPITCH + c0 + c] =
                __float2half(__builtin_amdgcn_exp2f(fminf(Mv * MS_SCALE, 15.9f)));
        }
    }
    __syncthreads();
    for (int idx = tid; idx < ROWS * (MPITCH - NTOK); idx += 1024) {
        int r = idx >> 6, k = idx & 63;
        Ms[r * MPITCH + NTOK + k] = __float2half(0.f);
    }
    __syncthreads();

    int* cnt = counters + b * 16;

    for (int it = 1; it <= ITERS; ++it) {
        if (it > 1) {
            // combine colsums -> beta_hat; owner re-adds -s_kept (commutative zeroing)
            if (tid < NTOK) {
                const int qr = (it - 1) & 1, qw = it & 1;
                float s = __hip_atomic_load(&Pacc[(size_t)(qr * BSZ + b) * NTOK + tid],
                                            __ATOMIC_RELAXED, __HIP_MEMORY_SCOPE_AGENT);
                float bf = CSCALE * __builtin_amdgcn_rcpf(s);
                v_l[tid] = bf;
                v_lh[tid] = __float2half(bf);
                if (tid >= r0 && tid < r0 + ROWS) {
                    if (s_kept != 0.f)
                        dummy += __hip_atomic_fetch_add(
                            &Pacc[(size_t)(qw * BSZ + b) * NTOK + tid], -s_kept,
                            __ATOMIC_RELAXED, __HIP_MEMORY_SCOPE_AGENT);
                    s_kept = s;
                }
            }
            __syncthreads();
        }
        // ---- u-pass: wave per row; K row via b128; beta in regs ----
#ifdef HAVE_FDOT2
        const int4 bm = *(const int4*)(v_lh + 8 * lane);           // cols 8L..8L+7
        const int  bt2 = *(const int*)(v_lh + 512 + 2 * lane);     // cols 512+2L
#else
        const float4 bm0 = *(const float4*)(v_l + 8 * lane);
        const float4 bm1 = *(const float4*)(v_l + 8 * lane + 4);
        const float2 bt2f = *(const float2*)(v_l + 512 + 2 * lane);
#endif
        for (int r = wv; r < ROWS; r += 16) {
            const int4 kr = *(const int4*)(Ms + r * MPITCH + 8 * lane);
            const int  kt = *(const int*)(Ms + r * MPITCH + 512 + 2 * lane);
            float a;
#ifdef HAVE_FDOT2
            a = __builtin_amdgcn_fdot2(bch2(kr.x), bch2(bm.x), 0.f, false);
            a = __builtin_amdgcn_fdot2(bch2(kr.y), bch2(bm.y), a, false);
            a = __builtin_amdgcn_fdot2(bch2(kr.z), bch2(bm.z), a, false);
            a = __builtin_amdgcn_fdot2(bch2(kr.w), bch2(bm.w), a, false);
            a = __builtin_amdgcn_fdot2(bch2(kt), bch2(bt2), a, false);
#else
            a = 0.f;
            float2 f0 = __half22float2(bchh(kr.x)), f1 = __half22float2(bchh(kr.y));
            float2 f2 = __half22float2(bchh(kr.z)), f3 = __half22float2(bchh(kr.w));
            float2 ft = __half22float2(bchh(kt));
            a = fmaf(f0.x, bm0.x, a); a = fmaf(f0.y, bm0.y, a);
            a = fmaf(f1.x, bm0.z, a); a = fmaf(f1.y, bm0.w, a);
            a = fmaf(f2.x, bm1.x, a); a = fmaf(f2.y, bm1.y, a);
            a = fmaf(f3.x, bm1.z, a); a = fmaf(f3.y, bm1.w, a);
            a = fmaf(ft.x, bt2f.x, a); a = fmaf(ft.y, bt2f.y, a);
#endif
            a = wave_sum63(a);
            if (lane == 63) u_l[r] = CSCALE * __builtin_amdgcn_rcpf(a);
        }
        __syncthreads();
        // ---- v-pass: thread owns col pair over ALL 36 rows; alpha via readlane ----
        if (tid < 288) {
            float areg = u_l[lane < ROWS ? lane : 0];
            const __half* colp = Ms + 2 * tid;
            float a0 = 0.f, a1 = 0.f;
#pragma unroll
            for (int nn = 0; nn < ROWS; nn++) {
                float an = __int_as_float(
                    __builtin_amdgcn_readlane(__float_as_int(areg), nn));
                float2 f = __half22float2(*(const __half2*)(colp + nn * MPITCH));
                a0 = fmaf(f.x, an, a0);
                a1 = fmaf(f.y, an, a1);
            }
            float* pp = &Pacc[(size_t)((it & 1) * BSZ + b) * NTOK + 2 * tid];
            dummy += __hip_atomic_fetch_add(pp, a0, __ATOMIC_RELAXED, __HIP_MEMORY_SCOPE_AGENT);
            dummy += __hip_atomic_fetch_add(pp + 1, a1, __ATOMIC_RELAXED, __HIP_MEMORY_SCOPE_AGENT);
        }
        // ---- per-batch barrier (relaxed; syncthreads drains vmcnt first) ----
        __syncthreads();
        if (tid == 0) {
            __hip_atomic_fetch_add(cnt, 1, __ATOMIC_RELAXED, __HIP_MEMORY_SCOPE_AGENT);
            const int target = WGB * it;
            while (__hip_atomic_load(cnt, __ATOMIC_RELAXED, __HIP_MEMORY_SCOPE_AGENT) < target)
                __builtin_amdgcn_s_sleep(1);
        }
        __syncthreads();
    }

    // ---- final: beta(50) from parity 0; sum(T*M) over own slice ----
    if (tid < NTOK) {
        float s = __hip_atomic_load(&Pacc[(size_t)b * NTOK + tid],
                                    __ATOMIC_RELAXED, __HIP_MEMORY_SCOPE_AGENT);
        v_l[tid] = CSCALE * __builtin_amdgcn_rcpf(s);
    }
    __syncthreads();
    float acc = 0.f;
    for (int idx = tid; idx < ROWS * NTOK; idx += 1024) {
        int r = idx / NTOK, m = idx - r * NTOK;
        float kf = __half2float(Ms[r * MPITCH + m]);
        float t = kf * u_l[r] * v_l[m];                    // = C*N*T
        acc = fmaf(t, __builtin_amdgcn_logf(kf), acc);     // log2(K) = M * 10*log2e
    }
#pragma unroll
    for (int off = 32; off > 0; off >>= 1) acc += __shfl_xor(acc, off, 64);
    if (lane == 0) red[wv] = acc;
    __syncthreads();
    if (tid == 0) {
        float s = 0.f;
#pragma unroll
        for (int w = 0; w < 16; w++) s += red[w];
        float old = __hip_atomic_fetch_add(gsum, s * FIN_WG,
                                           __ATOMIC_RELAXED, __HIP_MEMORY_SCOPE_AGENT);
        int* dptr = done + ((old == -1.2345678e33f) ? 1 : 0);
        int prev = __hip_atomic_fetch_add(dptr, 1, __ATOMIC_RELAXED, __HIP_MEMORY_SCOPE_AGENT);
        if (prev == NWG - 1) {
            float tot = __hip_atomic_load(gsum, __ATOMIC_RELAXED, __HIP_MEMORY_SCOPE_AGENT);
            out[0] = tot * (1.0f / BSZ);
        }
    }
    if (dummy == -1.2345678e33f) dummyout[blockIdx.x] = 1.f;
}

extern "C" void kernel_launch(void* const* d_in, const int* in_sizes, int n_in,
                              void* d_out, int out_size, void* d_ws, size_t ws_size,
                              hipStream_t stream) {
    const float* feat_s = (const float*)d_in[0];
    const float* feat_t = (const float*)d_in[1];
    const float* Ws = (const float*)d_in[2];
    const float* bs = (const float*)d_in[3];
    const float* Wt = (const float*)d_in[4];
    const float* bt = (const float*)d_in[5];

    char* ws = (char*)d_ws;
    int* counters  = (int*)(ws + OFF_CNT);
    int* done      = (int*)(ws + OFF_DONE);
    float* gsum    = (float*)(ws + OFF_GSUM);
    float* dummyo  = (float*)(ws + OFF_DUMMY);
    float* sumsq   = (float*)(ws + OFF_SQS);
    float* Pacc    = (float*)(ws + OFF_PACC);
    __half* xs     = (__half*)(ws + OFF_XS);
    __half* xt     = (__half*)(ws + OFF_XT);
    float* out = (float*)d_out;

    (void)hipMemsetAsync(ws, 0, MEMSET_BYTES, stream);

    hipLaunchKernelGGL(k1_proj, dim3(9, 32, 2), dim3(256), 0, stream,
                       feat_s, feat_t, Ws, bs, Wt, bt, xs, xt, sumsq);

    (void)hipFuncSetAttribute((const void*)k4_sinkhorn,
                              hipFuncAttributeMaxDynamicSharedMemorySize, SMEM_BYTES);
    hipLaunchKernelGGL(k4_sinkhorn, dim3(NWG), dim3(1024), SMEM_BYTES, stream,
                       xs, xt, sumsq, Pacc, counters, done, gsum, dummyo, out);
}

// Round 7
// 663.437 us; speedup vs baseline: 1.0092x; 1.0092x over previous
//
#include <hip/hip_runtime.h>
#include <hip/hip_fp16.h>

// Problem constants
#define BSZ 32
#define CS_ 640
#define CT_ 768
#define NTOK 576
#define HID 64
#define ITERS 50
#define WGB 16           // slices (wgs) per batch
#define ROWS 36          // rows of K per slice
#define NWG 256          // wgs; each serves part w>>4 of batches (w&15) and 16+(w&15)
#define MPITCH 640       // halves per K row (576 real + 64 pad of 0)
#define XPITCH 68        // halves per staged x row

#define MS_SCALE 14.426950408889634f      // 10*log2(e): K = exp2(M*MS_SCALE) = e^{M/reg}
#define M_FROM_MSP 0.06931471805599453f   // ln2/10
#define CSCALE 8192.0f                    // uniform Sinkhorn scaling constant
#define FIN_WG (M_FROM_MSP / (8192.0f * 576.0f))

// Workspace layout (bytes)
#define OFF_CNT 0              // 32 barrier counters, 64B apart
#define OFF_DONE 2048
#define OFF_GSUM 2056
#define OFF_DUMMY 2112         // keep-alive sink
#define OFF_SQS 4160           // sumsq [2][32][64] f32
#define OFF_PACC 20544         // colsum accumulators [2][32][576] f32 = 147456
#define MEMSET_BYTES 168000
#define OFF_XS 168000          // xs fp16 [32][576][64]
#define OFF_XT 2527296         // xt fp16 [32][576][64]

// k4 LDS layout (bytes); total 112,640 -> 1 wg/CU
#define L_KA 0                 // 36*640*2 = 46080
#define L_KB 46080             // 46080
#define L_UA 92160             // 36*4
#define L_UB 92304
#define L_VA 92448             // 640*4
#define L_VB 95008
#define L_VHA 97568            // 640*2 (fp16, 16B aligned)
#define L_VHB 98848
#define L_RED 100160           // 16*4
#define L_UNION 100256         // build: ssc 256 | stc 256 | sqs 160 | sqt 2304 | xs_l 4896 | xt_l 4352
#define SMEM_BYTES 112640

typedef _Float16 h2_t __attribute__((ext_vector_type(2)));

#if defined(__has_builtin)
#if __has_builtin(__builtin_amdgcn_fdot2)
#define HAVE_FDOT2 1
#endif
#endif

__device__ __forceinline__ h2_t bch2(int x) { return __builtin_bit_cast(h2_t, x); }
__device__ __forceinline__ __half2 bchh(int x) { return __builtin_bit_cast(__half2, x); }

template <int CTRL, int RM>
__device__ __forceinline__ float dpp_add_step(float x) {
    int y = __builtin_amdgcn_update_dpp(0, __float_as_int(x), CTRL, RM, 0xf, false);
    return x + __int_as_float(y);
}
__device__ __forceinline__ float wave_sum63(float x) {
    x = dpp_add_step<0x111, 0xf>(x);
    x = dpp_add_step<0x112, 0xf>(x);
    x = dpp_add_step<0x114, 0xf>(x);
    x = dpp_add_step<0x118, 0xf>(x);
    x = dpp_add_step<0x142, 0xa>(x);
    x = dpp_add_step<0x143, 0xc>(x);
    return x;   // lane 63 = total
}

// ---------------------------------------------------------------------------
// K1 (streaming): block = 512 thr (8 waves), one 64-token tile. Wave = 8 h.
// feat reads coalesced (64 tokens/lane-row); 8 waves of a block share lines
// via L1 (4x occupancy vs round-3's 128-thr version; no LDS barriers).
// ---------------------------------------------------------------------------
template <int C>
__device__ __forceinline__ void proj_stream(
    const float* __restrict__ feat,   // [C][576] this batch
    const float* __restrict__ W,      // [64][C]
    const float* __restrict__ bias,
    __half* __restrict__ out,         // [576][64] this batch
    float* __restrict__ sq,           // [64]
    int nblk)
{
    const int tid = threadIdx.x;
    const int lane = tid & 63;
    const int wv = __builtin_amdgcn_readfirstlane((int)(tid >> 6));  // 0..7
    const int h0 = wv * 8;
    const int n = nblk * 64 + lane;

    float acc[8];
#pragma unroll
    for (int i = 0; i < 8; i++) acc[i] = 0.f;

    const float* fb = feat + n;
#pragma unroll 2
    for (int c0 = 0; c0 < C; c0 += 8) {
        float f[8];
#pragma unroll
        for (int j = 0; j < 8; j++) f[j] = fb[(size_t)(c0 + j) * NTOK];
#pragma unroll
        for (int hh = 0; hh < 8; hh++) {
            const float* wr = W + (size_t)(h0 + hh) * C + c0;
#pragma unroll
            for (int j = 0; j < 8; j++) acc[hh] = fmaf(f[j], wr[j], acc[hh]);
        }
    }
#pragma unroll
    for (int hh = 0; hh < 8; hh++) acc[hh] += bias[h0 + hh];

    __half2 hp[4];
#pragma unroll
    for (int hh = 0; hh < 8; hh += 2) hp[hh >> 1] = __floats2half2_rn(acc[hh], acc[hh + 1]);
    *(float4*)(out + (size_t)n * HID + h0) = *(const float4*)hp;

#pragma unroll
    for (int hh = 0; hh < 8; hh++) {
        float v2 = acc[hh] * acc[hh];
#pragma unroll
        for (int off = 32; off > 0; off >>= 1) v2 += __shfl_xor(v2, off, 64);
        if (lane == 0) atomicAdd(sq + h0 + hh, v2);
    }
}

__global__ __launch_bounds__(512, 4) void k1_proj(
    const float* __restrict__ feat_s, const float* __restrict__ feat_t,
    const float* __restrict__ Ws, const float* __restrict__ bs,
    const float* __restrict__ Wt, const float* __restrict__ bt,
    __half* __restrict__ xs, __half* __restrict__ xt, float* __restrict__ sumsq)
{
    const int nblk = blockIdx.x, b = blockIdx.y, st = blockIdx.z;
    if (st == 0) {
        proj_stream<CS_>(feat_s + (size_t)b * CS_ * NTOK, Ws, bs,
                         xs + (size_t)b * NTOK * HID, sumsq + b * 64, nblk);
    } else {
        proj_stream<CT_>(feat_t + (size_t)b * CT_ * NTOK, Wt, bt,
                         xt + (size_t)b * NTOK * HID, sumsq + (BSZ + b) * 64, nblk);
    }
}

// ---------------------------------------------------------------------------
// k4 helpers
// ---------------------------------------------------------------------------
__device__ __forceinline__ void group_wait(int* cnt, int target) {
    // only lane 0 of the combine waves (tid<576) spins; wave lockstep releases all
    if ((threadIdx.x & 63) == 0 && (threadIdx.x >> 6) < 9) {
        while (__hip_atomic_load(cnt, __ATOMIC_RELAXED, __HIP_MEMORY_SCOPE_AGENT) < target)
            __builtin_amdgcn_s_sleep(1);
    }
}

__device__ __forceinline__ float combine_phase(
    float* __restrict__ Pr, float* __restrict__ Pw,
    float* __restrict__ vf, __half* __restrict__ vh,
    int r0, float s_kept, float& dummy)
{
    const int tid = threadIdx.x;
    if (tid < NTOK) {
        float s = __hip_atomic_load(&Pr[tid], __ATOMIC_RELAXED, __HIP_MEMORY_SCOPE_AGENT);
        float bf = CSCALE * __builtin_amdgcn_rcpf(s);
        vf[tid] = bf;
        vh[tid] = __float2half(bf);
        if (tid >= r0 && tid < r0 + ROWS) {
            if (s_kept != 0.f)
                dummy += __hip_atomic_fetch_add(&Pw[tid], -s_kept,
                                                __ATOMIC_RELAXED, __HIP_MEMORY_SCOPE_AGENT);
            s_kept = s;
        }
    }
    return s_kept;
}

__device__ __forceinline__ void u_pass(const __half* __restrict__ K,
                                       const __half* __restrict__ vh,
                                       const float* __restrict__ vf,
                                       float* __restrict__ u)
{
    const int lane = threadIdx.x & 63, wv = threadIdx.x >> 6;
#ifdef HAVE_FDOT2
    const int4 bm = *(const int4*)(vh + 8 * lane);
    const int  b2 = *(const int*)(vh + 512 + 2 * lane);
    (void)vf;
#else
    const float4 bm0 = *(const float4*)(vf + 8 * lane);
    const float4 bm1 = *(const float4*)(vf + 8 * lane + 4);
    const float2 b2f = *(const float2*)(vf + 512 + 2 * lane);
#endif
    for (int r = wv; r < ROWS; r += 16) {
        const int4 kr = *(const int4*)(K + r * MPITCH + 8 * lane);
        const int  kt = *(const int*)(K + r * MPITCH + 512 + 2 * lane);
        float a;
#ifdef HAVE_FDOT2
        a = __builtin_amdgcn_fdot2(bch2(kr.x), bch2(bm.x), 0.f, false);
        a = __builtin_amdgcn_fdot2(bch2(kr.y), bch2(bm.y), a, false);
        a = __builtin_amdgcn_fdot2(bch2(kr.z), bch2(bm.z), a, false);
        a = __builtin_amdgcn_fdot2(bch2(kr.w), bch2(bm.w), a, false);
        a = __builtin_amdgcn_fdot2(bch2(kt), bch2(b2), a, false);
#else
        a = 0.f;
        float2 f0 = __half22float2(bchh(kr.x)), f1 = __half22float2(bchh(kr.y));
        float2 f2 = __half22float2(bchh(kr.z)), f3 = __half22float2(bchh(kr.w));
        float2 ft = __half22float2(bchh(kt));
        a = fmaf(f0.x, bm0.x, a); a = fmaf(f0.y, bm0.y, a);
        a = fmaf(f1.x, bm0.z, a); a = fmaf(f1.y, bm0.w, a);
        a = fmaf(f2.x, bm1.x, a); a = fmaf(f2.y, bm1.y, a);
        a = fmaf(f3.x, bm1.z, a); a = fmaf(f3.y, bm1.w, a);
        a = fmaf(ft.x, b2f.x, a); a = fmaf(ft.y, b2f.y, a);
#endif
        a = wave_sum63(a);
        if (lane == 63) u[r] = CSCALE * __builtin_amdgcn_rcpf(a);
    }
}

__device__ __forceinline__ void v_pass(const __half* __restrict__ K,
                                       const float* __restrict__ u,
                                       float* __restrict__ Pw, float& dummy)
{
    const int tid = threadIdx.x;
    if (tid < 288) {
        const int lane = tid & 63;
        float areg = u[lane < ROWS ? lane : 0];
        const __half* colp = K + 2 * tid;
        float a0 = 0.f, a1 = 0.f;
#pragma unroll
        for (int nn = 0; nn < ROWS; nn++) {
            float an = __int_as_float(__builtin_amdgcn_readlane(__float_as_int(areg), nn));
            float2 f = __half22float2(*(const __half2*)(colp + nn * MPITCH));
            a0 = fmaf(f.x, an, a0);
            a1 = fmaf(f.y, an, a1);
        }
        dummy += __hip_atomic_fetch_add(&Pw[2 * tid], a0,
                                        __ATOMIC_RELAXED, __HIP_MEMORY_SCOPE_AGENT);
        dummy += __hip_atomic_fetch_add(&Pw[2 * tid + 1], a1,
                                        __ATOMIC_RELAXED, __HIP_MEMORY_SCOPE_AGENT);
    }
}

__device__ void build_slice(const __half* __restrict__ xsh,
                            const __half* __restrict__ xth,
                            const float* __restrict__ sumsq,
                            int b, int r0, __half* __restrict__ K, char* un)
{
    float* ssc = (float*)(un);
    float* stc = (float*)(un + 256);
    float* sqs = (float*)(un + 512);
    float* sqt = (float*)(un + 672);
    __half* xs_l = (__half*)(un + 2976);
    __half* xt_l = (__half*)(un + 7872);
    const int tid = threadIdx.x;

    if (tid < 64) {
        ssc[tid] = 1.0f / fmaxf(sqrtf(sumsq[b * 64 + tid]), 1e-12f);
    } else if (tid < 128) {
        stc[tid - 64] = 1.0f / fmaxf(sqrtf(sumsq[BSZ * 64 + b * 64 + (tid - 64)]), 1e-12f);
    }
    __syncthreads();
    for (int idx = tid; idx < ROWS * 64; idx += 1024) {
        int r = idx >> 6, h = idx & 63;
        xs_l[r * XPITCH + h] =
            __float2half(__half2float(xsh[((size_t)b * NTOK + r0 + r) * 64 + h]) * ssc[h]);
    }
    if (tid < NTOK) {
        const __half* tp = xth + ((size_t)b * NTOK + tid) * 64;
        float s = 0.f;
#pragma unroll
        for (int h = 0; h < 64; h++) { float v = __half2float(tp[h]) * stc[h]; s = fmaf(v, v, s); }
        sqt[tid] = s;
    }
    __syncthreads();
    if (tid < ROWS) {
        float s = 0.f;
#pragma unroll
        for (int h = 0; h < 64; h++) { float v = __half2float(xs_l[tid * XPITCH + h]); s = fmaf(v, v, s); }
        sqs[tid] = s;
    }
    for (int c0 = 0; c0 < NTOK; c0 += 32) {
        __syncthreads();
        for (int idx = tid; idx < 32 * 64; idx += 1024) {
            int m = idx >> 6, h = idx & 63;
            xt_l[m * XPITCH + h] =
                __float2half(__half2float(xth[((size_t)b * NTOK + c0 + m) * 64 + h]) * stc[h]);
        }
        __syncthreads();
        for (int idx = tid; idx < ROWS * 32; idx += 1024) {
            int r = idx >> 5, c = idx & 31;
            const __half2* xr = (const __half2*)(xs_l + r * XPITCH);
            const __half2* tr = (const __half2*)(xt_l + c * XPITCH);
            float d = 0.f;
#pragma unroll
            for (int h2 = 0; h2 < 32; h2++) {
                float2 av = __half22float2(xr[h2]);
                float2 tv = __half22float2(tr[h2]);
                d = fmaf(av.x, tv.x, d);
                d = fmaf(av.y, tv.y, d);
            }
            float Mv = fmaxf(sqs[r] + sqt[c] - 2.f * d, 0.f);
            K[r * MPITCH + c0 + c] =
                __float2half(__builtin_amdgcn_exp2f(fminf(Mv * MS_SCALE, 15.9f)));
        }
    }
    __syncthreads();
    for (int idx = tid; idx < ROWS * (MPITCH - NTOK); idx += 1024) {
        int r = idx >> 6, k = idx & 63;
        K[r * MPITCH + NTOK + k] = __float2half(0.f);
    }
}

// ---------------------------------------------------------------------------
// K4: persistent Sinkhorn, linear domain, TWO batches per wg (software
// pipeline). Remote round trips of batch A overlap compute of batch B.
// Arrivals posted at the first post-drain barrier (S3 for A, next-S1 for B).
// ---------------------------------------------------------------------------
__global__ __launch_bounds__(1024, 4) void k4_sinkhorn(
    const __half* __restrict__ xsh, const __half* __restrict__ xth,
    const float* __restrict__ sumsq, float* __restrict__ Pacc,
    int* __restrict__ counters, int* __restrict__ done,
    float* __restrict__ gsum, float* __restrict__ dummyout,
    float* __restrict__ out)
{
    extern __shared__ char smem[];
    __half* KA = (__half*)(smem + L_KA);
    __half* KB = (__half*)(smem + L_KB);
    float* uA = (float*)(smem + L_UA);
    float* uB = (float*)(smem + L_UB);
    float* vA = (float*)(smem + L_VA);
    float* vB = (float*)(smem + L_VB);
    __half* vhA = (__half*)(smem + L_VHA);
    __half* vhB = (__half*)(smem + L_VHB);
    float* red = (float*)(smem + L_RED);
    char* un = smem + L_UNION;

    const int tid = threadIdx.x;
    const int w = blockIdx.x;
    const int bA = w & 15;
    const int bB = 16 + (w & 15);
    const int part = w >> 4;
    const int r0 = part * ROWS;
    const int lane = tid & 63, wv = tid >> 6;
    float dummy = 0.f, s_keptA = 0.f, s_keptB = 0.f;

    build_slice(xsh, xth, sumsq, bA, r0, KA, un);
    __syncthreads();
    build_slice(xsh, xth, sumsq, bB, r0, KB, un);
    for (int m = tid; m < MPITCH; m += 1024) {
        float b0 = (m < NTOK) ? 1.f : 0.f;
        vA[m] = b0; vB[m] = b0;
        vhA[m] = __float2half(b0); vhB[m] = __float2half(b0);
    }
    __syncthreads();

    int* cntA = counters + bA * 16;
    int* cntB = counters + bB * 16;
    float* PA0 = Pacc + (size_t)bA * NTOK;
    float* PB0 = Pacc + (size_t)bB * NTOK;
    const size_t PPAR = (size_t)BSZ * NTOK;

    for (int it = 1; it <= ITERS; ++it) {
        const int qr = (it - 1) & 1, qw = it & 1;
        // ---------- A phase ----------
        if (it > 1) {
            group_wait(cntA, WGB * (it - 1));
            s_keptA = combine_phase(PA0 + PPAR * qr, PA0 + PPAR * qw,
                                    vA, vhA, r0, s_keptA, dummy);
        }
        __syncthreads();                                    // S1: vA pub; drains prev atomics_B + A-loads
        if (it > 1 && tid == 0)
            __hip_atomic_fetch_add(cntB, 1, __ATOMIC_RELAXED, __HIP_MEMORY_SCOPE_AGENT); // arrive_B(it-1)
        u_pass(KA, vhA, vA, uA);
        __syncthreads();                                    // S2
        v_pass(KA, uA, PA0 + PPAR * qw, dummy);             // atomics_A in flight
        // ---------- B phase ----------
        if (it > 1) {
            group_wait(cntB, WGB * (it - 1));
            s_keptB = combine_phase(PB0 + PPAR * qr, PB0 + PPAR * qw,
                                    vB, vhB, r0, s_keptB, dummy);
        }
        __syncthreads();                                    // S3: vB pub; drains atomics_A + B-loads
        if (tid == 0)
            __hip_atomic_fetch_add(cntA, 1, __ATOMIC_RELAXED, __HIP_MEMORY_SCOPE_AGENT); // arrive_A(it)
        u_pass(KB, vhB, vB, uB);
        __syncthreads();                                    // S4
        v_pass(KB, uB, PB0 + PPAR * qw, dummy);             // atomics_B in flight
    }
    __syncthreads();                                        // drain atomics_B(50)
    if (tid == 0)
        __hip_atomic_fetch_add(cntB, 1, __ATOMIC_RELAXED, __HIP_MEMORY_SCOPE_AGENT);     // arrive_B(50)

    // ---- final: parity 0 holds it=50 colsums ----
    group_wait(cntA, WGB * ITERS);
    if (tid < NTOK) {
        float s = __hip_atomic_load(&PA0[tid], __ATOMIC_RELAXED, __HIP_MEMORY_SCOPE_AGENT);
        vA[tid] = CSCALE * __builtin_amdgcn_rcpf(s);
    }
    group_wait(cntB, WGB * ITERS);
    if (tid < NTOK) {
        float s = __hip_atomic_load(&PB0[tid], __ATOMIC_RELAXED, __HIP_MEMORY_SCOPE_AGENT);
        vB[tid] = CSCALE * __builtin_amdgcn_rcpf(s);
    }
    __syncthreads();
    float acc = 0.f;
    for (int idx = tid; idx < ROWS * NTOK; idx += 1024) {
        int r = idx / NTOK, m = idx - r * NTOK;
        float ka = __half2float(KA[r * MPITCH + m]);
        acc = fmaf(ka * uA[r] * vA[m], __builtin_amdgcn_logf(ka), acc);
        float kb = __half2float(KB[r * MPITCH + m]);
        acc = fmaf(kb * uB[r] * vB[m], __builtin_amdgcn_logf(kb), acc);
    }
#pragma unroll
    for (int off = 32; off > 0; off >>= 1) acc += __shfl_xor(acc, off, 64);
    if (lane == 0) red[wv] = acc;
    __syncthreads();
    if (tid == 0) {
        float s = 0.f;
#pragma unroll
        for (int ww = 0; ww < 16; ww++) s += red[ww];
        float old = __hip_atomic_fetch_add(gsum, s * FIN_WG,
                                           __ATOMIC_RELAXED, __HIP_MEMORY_SCOPE_AGENT);
        int* dptr = done + ((old == -1.2345678e33f) ? 1 : 0);
        int prev = __hip_atomic_fetch_add(dptr, 1, __ATOMIC_RELAXED, __HIP_MEMORY_SCOPE_AGENT);
        if (prev == NWG - 1) {
            float tot = __hip_atomic_load(gsum, __ATOMIC_RELAXED, __HIP_MEMORY_SCOPE_AGENT);
            out[0] = tot * (1.0f / BSZ);
        }
    }
    if (dummy == -1.2345678e33f) dummyout[blockIdx.x] = 1.f;
}

extern "C" void kernel_launch(void* const* d_in, const int* in_sizes, int n_in,
                              void* d_out, int out_size, void* d_ws, size_t ws_size,
                              hipStream_t stream) {
    const float* feat_s = (const float*)d_in[0];
    const float* feat_t = (const float*)d_in[1];
    const float* Ws = (const float*)d_in[2];
    const float* bs = (const float*)d_in[3];
    const float* Wt = (const float*)d_in[4];
    const float* bt = (const float*)d_in[5];

    char* ws = (char*)d_ws;
    int* counters  = (int*)(ws + OFF_CNT);
    int* done      = (int*)(ws + OFF_DONE);
    float* gsum    = (float*)(ws + OFF_GSUM);
    float* dummyo  = (float*)(ws + OFF_DUMMY);
    float* sumsq   = (float*)(ws + OFF_SQS);
    float* Pacc    = (float*)(ws + OFF_PACC);
    __half* xs     = (__half*)(ws + OFF_XS);
    __half* xt     = (__half*)(ws + OFF_XT);
    float* out = (float*)d_out;

    (void)hipMemsetAsync(ws, 0, MEMSET_BYTES, stream);

    hipLaunchKernelGGL(k1_proj, dim3(9, 32, 2), dim3(512), 0, stream,
                       feat_s, feat_t, Ws, bs, Wt, bt, xs, xt, sumsq);

    (void)hipFuncSetAttribute((const void*)k4_sinkhorn,
                              hipFuncAttributeMaxDynamicSharedMemorySize, SMEM_BYTES);
    hipLaunchKernelGGL(k4_sinkhorn, dim3(NWG), dim3(1024), SMEM_BYTES, stream,
                       xs, xt, sumsq, Pacc, counters, done, gsum, dummyo, out);
}